// Round 15
// baseline (197.571 us; speedup 1.0000x reference)
//
#include <hip/hip_runtime.h>
#include <hip/hip_bf16.h>

typedef unsigned long long u64;
typedef unsigned int u32;
typedef __attribute__((ext_vector_type(4))) double f64x4;

#define NB   64
#define NPOS 1024
#define NOUT 25
#define NCLS 20
#define WROW 32            // f64 weights per channel row, padded to 256 B

// ---- workspace layout (bytes) ----
#define OFF_W64   0          // double wpad[512*32] = 131072
#define OFF_B64   131072     // double b64[25]      = 200 (pad to 131328)
#define OFF_MASK  131328     // u64    masksT[64][16][1024] = 8388608 -> end 8519936

// ---------------- kernel 0: weights -> f64, layout [c][32] (pad 0) -----------
__global__ __launch_bounds__(256) void k_cvt(const float* __restrict__ w,
                                             const float* __restrict__ bias,
                                             double* __restrict__ wpad,
                                             double* __restrict__ b64)
{
    int idx = blockIdx.x * 256 + threadIdx.x;
    if (idx < 512 * WROW) {
        int c = idx >> 5, o = idx & 31;
        wpad[idx] = (o < NOUT) ? (double)w[o * 512 + c] : 0.0;
    }
    if (idx < NOUT) b64[idx] = (double)bias[idx];
}

// ---------------- f64 epilogue: sigmoid/softmax/argmax + box decode ----------
__device__ __forceinline__ void epilogue(const double* __restrict__ acc,
                                         const double* __restrict__ b64,
                                         int n, int gi,
                                         float* __restrict__ boxes_out,
                                         float* __restrict__ scores_out,
                                         float* __restrict__ cls_out)
{
    double p[NOUT];
#pragma unroll
    for (int o = 0; o < NOUT; ++o) p[o] = acc[o] + b64[o];

    double conf = 1.0 / (1.0 + exp(-p[0]));
    double m = p[1]; int ci = 0;
#pragma unroll
    for (int i = 2; i <= NCLS; ++i) {
        if (p[i] > m) { m = p[i]; ci = i - 1; }
    }
    double ssum = 0.0;
#pragma unroll
    for (int i = 0; i < NCLS; ++i) ssum += exp(p[1 + i] - m);
    double best = conf / ssum;

    int gx = n & 31, gy = n >> 5;
    double sx = 1.0 / (1.0 + exp(-p[21]));
    double sy = 1.0 / (1.0 + exp(-p[22]));
    double cx = (sx + (double)gx) * 32.0;
    double cy = (sy + (double)gy) * 32.0;
    double bw = exp(p[23]), bh = exp(p[24]);
    double x1 = (cx - bw * 0.5) * (1.0 / 1024.0);
    double y1 = (cy - bh * 0.5) * (1.0 / 1024.0);
    double x2 = (cx + bw * 0.5) * (1.0 / 1024.0);
    double y2 = (cy + bh * 0.5) * (1.0 / 1024.0);
    x1 = fmin(fmax(x1, 0.0), 1.0); y1 = fmin(fmax(y1, 0.0), 1.0);
    x2 = fmin(fmax(x2, 0.0), 1.0); y2 = fmin(fmax(y2, 0.0), 1.0);

    ((float4*)boxes_out)[gi] = make_float4((float)x1, (float)y1, (float)x2, (float)y2);
    scores_out[gi] = (float)best;
    cls_out[gi]    = (float)ci;
}

// ---------------- kernel 1: f64 MFMA GEMM, LDS-staged, pd unioned (R13) ------
__global__ __launch_bounds__(256, 4) void k_main(const float* __restrict__ feat,
                                                 const double* __restrict__ wpad_g,
                                                 const double* __restrict__ b64,
                                                 float* __restrict__ boxes_out,
                                                 float* __restrict__ scores_out,
                                                 float* __restrict__ cls_out)
{
    __shared__ __align__(16) char smem[32768];
    float*  AbF = (float*)smem;                    // [2][32*64] floats
    double* BbF = (double*)(smem + 16384);         // [2][32*32] doubles
    double (*pd)[33] = (double(*)[33])smem;        // [64][33], post-loop reuse

    const int b   = blockIdx.y;
    const int tid = threadIdx.x;
    const int l   = tid & 63;
    const int wv  = tid >> 6;
    const int pg  = wv >> 1;          // position half (32 pos)
    const int oh  = wv & 1;           // out half (16 outs)
    const int n0  = blockIdx.x * 64;

    // --- runtime D-row calibration: A[m][0]=m, B[0][n]=1 => D[m][n]=m -------
    double ca = ((l >> 4) == 0) ? (double)(l & 15) : 0.0;
    double cb = ((l >> 4) == 0) ? 1.0 : 0.0;
    f64x4 cd = {0.0, 0.0, 0.0, 0.0};
    cd = __builtin_amdgcn_mfma_f64_16x16x4f64(ca, cb, cd, 0, 0, 0);
    int rmap[4];
#pragma unroll
    for (int v = 0; v < 4; ++v) {
        int r = (int)(cd[v] + 0.5);
        rmap[v] = (r < 0) ? 0 : (r > 15 ? 15 : r);
    }

    const float* __restrict__ featb = feat + (size_t)b * 512 * NPOS + n0;

#define A_SRC(C0, IT) (((const float4*)(featb + (size_t)((C0) + wv*8 + (IT)*4 + (l>>4)) * NPOS)) + (l & 15))
#define B_SRC(C0, IT) (((const double2*)(wpad_g + (size_t)((C0) + wv*8 + (IT)*4 + (l>>4)) * WROW)) + (l & 15))
#define A_DST(BUF, IT) ((float4*)(AbF + (BUF)*2048 + (wv*8 + (IT)*4) * 64 + l*4))
#define B_DST(BUF, IT) ((double2*)(BbF + (BUF)*1024 + (wv*8 + (IT)*4) * 32 + l*2))

    f64x4 acc0 = {0.0, 0.0, 0.0, 0.0};   // pos frag 0 (pg*32+0..15) x out-half
    f64x4 acc1 = {0.0, 0.0, 0.0, 0.0};   // pos frag 1 (pg*32+16..31)

    // prologue: stage chunk 0
    float4  ra0 = *A_SRC(0, 0), ra1 = *A_SRC(0, 1);
    double2 rb0 = *B_SRC(0, 0), rb1 = *B_SRC(0, 1);
    *A_DST(0, 0) = ra0;  *A_DST(0, 1) = ra1;
    *B_DST(0, 0) = rb0;  *B_DST(0, 1) = rb1;
    __syncthreads();

#pragma unroll 1
    for (int t = 0; t < 16; ++t) {
        const int buf = t & 1;
        const bool more = (t + 1) < 16;
        const int c1 = (t + 1) * 32;
        if (more) {                       // issue next-chunk loads (hide under MFMA)
            ra0 = *A_SRC(c1, 0);  ra1 = *A_SRC(c1, 1);
            rb0 = *B_SRC(c1, 0);  rb1 = *B_SRC(c1, 1);
        }
#pragma unroll
        for (int s = 0; s < 8; ++s) {     // 8 k-steps x 4 ch
            const int rowA = buf*2048 + (4*s + (l >> 4)) * 64 + pg * 32 + (l & 15);
            const int rowB = buf*1024 + (4*s + (l >> 4)) * 32 + oh * 16 + (l & 15);
            double av0 = (double)AbF[rowA];
            double av1 = (double)AbF[rowA + 16];
            double bv  = BbF[rowB];
            acc0 = __builtin_amdgcn_mfma_f64_16x16x4f64(av0, bv, acc0, 0, 0, 0);
            acc1 = __builtin_amdgcn_mfma_f64_16x16x4f64(av1, bv, acc1, 0, 0, 0);
        }
        if (more) {                       // write next chunk into alt buffer
            *A_DST(buf ^ 1, 0) = ra0;  *A_DST(buf ^ 1, 1) = ra1;
            *B_DST(buf ^ 1, 0) = rb0;  *B_DST(buf ^ 1, 1) = rb1;
        }
        __syncthreads();
    }
#undef A_SRC
#undef B_SRC
#undef A_DST
#undef B_DST

    // dump D to LDS as [pos][out] with calibrated row map (smem reused)
#pragma unroll
    for (int v = 0; v < 4; ++v) {
        int r0 = pg * 32 + rmap[v];
        pd[r0][oh * 16 + (l & 15)]      = acc0[v];
        pd[r0 + 16][oh * 16 + (l & 15)] = acc1[v];
    }
    __syncthreads();

    if (tid < 64) {
        double acc[NOUT];
#pragma unroll
        for (int o = 0; o < NOUT; ++o) acc[o] = pd[tid][o];
        int n = n0 + tid;
        epilogue(acc, b64, n, b * NPOS + n, boxes_out, scores_out, cls_out);
    }
}

// ---------------- kernel 2: fused per-batch NMS (sort + mask + scan) ---------
// One block (512 thr = 8 waves) per batch. All cross-phase data in LDS; the
// mask tiles round-trip through global masksT but are written and read by the
// SAME block (within-workgroup coherence across __syncthreads; no fences).
__global__ __launch_bounds__(512) void k_nms(const float* __restrict__ scores,
                                             const float* __restrict__ boxes,
                                             const float* __restrict__ cls,
                                             u64* __restrict__ masksT,
                                             float* __restrict__ keep_out)
{
    __shared__ u64    key[NPOS];      // 8192 B (sorted keys; low 32 = orig idx)
    __shared__ float4 sb[NPOS];       // 16384 B sorted boxes
    __shared__ float2 ac[NPOS];       // 8192 B  (area, cls bits)
    __shared__ u64    vw[16];         // valid bitmap (sorted positions)
    __shared__ u32    summ[16];       // per-64-row-group word flags
    const int b = blockIdx.x, tid = threadIdx.x;
    const int lane = tid & 63, wvv = tid >> 6;

    // ---- phase 1: key build + bitonic sort (desc score, stable) ----
    for (int p = tid; p < NPOS; p += 512) {
        u32 bits = __float_as_uint(scores[b * NPOS + p]);
        u32 d = ~(bits | 0x80000000u);
        key[p] = ((u64)d << 32) | (u32)p;
    }
    if (tid < 16) { vw[tid] = 0ull; summ[tid] = 0u; }
    __syncthreads();

    for (int k = 2; k <= NPOS; k <<= 1) {
        for (int j = k >> 1; j > 0; j >>= 1) {
            for (int idx = tid; idx < NPOS; idx += 512) {
                int l2 = idx ^ j;
                if (l2 > idx) {
                    u64 a = key[idx], c = key[l2];
                    bool up = ((idx & k) == 0);
                    if ((a > c) == up) { key[idx] = c; key[l2] = a; }
                }
            }
            __syncthreads();
        }
    }

    // ---- gather sorted boxes/areas/cls into LDS + valid bits ----
    for (int p = tid; p < NPOS; p += 512) {
        u64 kk = key[p];
        int idx = (int)(kk & 0xffffffffu);
        float4 bb = ((const float4*)boxes)[b * NPOS + idx];
        sb[p] = bb;
        ac[p] = make_float2((bb.z - bb.x) * (bb.w - bb.y),
                            __int_as_float((int)cls[b * NPOS + idx]));
        u32 sbits = (~(u32)(kk >> 32)) & 0x7fffffffu;
        if (__uint_as_float(sbits) > 0.01f)
            atomicOr(&vw[p >> 6], 1ull << (p & 63));
    }
    __syncthreads();

    // ---- phase 2: suppression mask; wave wvv owns words {wvv, 15-wvv} ----
#pragma unroll 1
    for (int wsel = 0; wsel < 2; ++wsel) {
        const int w = wsel ? (15 - wvv) : wvv;
        u64* __restrict__ mcol = masksT + (((size_t)b * 16 + w) << 10);
        const int jg = w * 64 + lane;
        float4 bj = sb[jg];
        float  aj = ac[jg].x;
        int    cj = __float_as_int(ac[jg].y);

#pragma unroll 1
        for (int t = 0; t <= w; ++t) {            // 64-row tiles, i < (w+1)*64
            u64 myword = 0ull;
#pragma unroll 1
            for (int s = 0; s < 64; s += 8) {
                u64 bits[8];
#pragma unroll
                for (int u = 0; u < 8; ++u) {
                    int i = t * 64 + s + u;
                    float4 bi = sb[i];            // wave-uniform broadcast
                    float2 a2 = ac[i];
                    float xx1 = fmaxf(bi.x, bj.x), yy1 = fmaxf(bi.y, bj.y);
                    float xx2 = fminf(bi.z, bj.z), yy2 = fminf(bi.w, bj.w);
                    float ww = fmaxf(1e-28f, xx2 - xx1);
                    float hh = fmaxf(1e-28f, yy2 - yy1);
                    float inter = ww * hh;
                    float uni = a2.x + aj - inter;
                    bool sup = (__float_as_int(a2.y) == cj) && (uni > 0.0f) &&
                               (inter > 0.5f * uni) && (jg > i);
                    bits[u] = __ballot(sup);
                }
#pragma unroll
                for (int u = 0; u < 8; ++u)
                    myword = (lane == s + u) ? bits[u] : myword;
            }
            if (__any(myword != 0ull)) {
                mcol[t * 64 + lane] = myword;
                if (lane == 0) atomicOr(&summ[t], 1u << w);
            }
        }
    }
    __syncthreads();   // mask stores drained (vmcnt) -> visible to wave 0

    // ---- phase 3: wave 0 sequential scan + scatter ----
    if (wvv == 0) {
        u64 keep = (lane < 16) ? vw[lane] : 0ull;
        u32 sv   = (lane < 16) ? summ[lane] : 0u;
        const u64* M = masksT + ((size_t)b << 14);
        int myrow = lane >> 4;
        int myw   = lane & 15;

#pragma unroll 1
        for (int G = 0; G < 16; ++G) {
            u32 gm = (u32)__shfl((int)sv, G);
            if (gm == 0u) continue;
#pragma unroll 1
            for (int g4 = 0; g4 < 16; ++g4) {
                u64 cur = 0ull;
                if ((gm >> myw) & 1u)
                    cur = M[((size_t)myw << 10) + G * 64 + g4 * 4 + myrow];
                if (__any(cur != 0ull)) {
#pragma unroll
                    for (int r = 0; r < 4; ++r) {
                        int i = G * 64 + g4 * 4 + r;
                        u64 kw = __shfl(keep, i >> 6);
                        if ((kw >> (i & 63)) & 1ull) {
                            u64 mm = __shfl(cur, r * 16 + myw);
                            if (lane < 16) keep &= ~mm;
                        }
                    }
                }
            }
        }

#pragma unroll
        for (int t = 0; t < 16; ++t) {
            int p = t * 64 + lane;
            u64 kw = __shfl(keep, t);
            float v = ((kw >> lane) & 1ull) ? 1.0f : 0.0f;
            keep_out[b * NPOS + (int)(key[p] & 0xffffffffu)] = v;
        }
    }
}

// ------------------------------------------------------------------------------
extern "C" void kernel_launch(void* const* d_in, const int* in_sizes, int n_in,
                              void* d_out, int out_size, void* d_ws, size_t ws_size,
                              hipStream_t stream)
{
    const float* feat = (const float*)d_in[0];
    const float* w    = (const float*)d_in[1];
    const float* bias = (const float*)d_in[2];

    float* out = (float*)d_out;
    float* boxes_out  = out;
    float* scores_out = out + NB * NPOS * 4;
    float* cls_out    = out + NB * NPOS * 5;
    float* keep_out   = out + NB * NPOS * 6;

    char* ws = (char*)d_ws;
    double* wpad  = (double*)(ws + OFF_W64);
    double* b64   = (double*)(ws + OFF_B64);
    u64*    masksT= (u64*)   (ws + OFF_MASK);

    hipLaunchKernelGGL(k_cvt,  dim3(64),     dim3(256), 0, stream, w, bias, wpad, b64);
    hipLaunchKernelGGL(k_main, dim3(16, 64), dim3(256), 0, stream, feat, wpad, b64,
                       boxes_out, scores_out, cls_out);
    hipLaunchKernelGGL(k_nms,  dim3(64),     dim3(512), 0, stream, scores_out,
                       boxes_out, cls_out, masksT, keep_out);
}

// Round 16
// 136.635 us; speedup vs baseline: 1.4460x; 1.4460x over previous
//
#include <hip/hip_runtime.h>
#include <hip/hip_bf16.h>

typedef unsigned long long u64;
typedef unsigned int u32;
typedef __attribute__((ext_vector_type(4))) double f64x4;

#define NB   64
#define NPOS 1024
#define NOUT 25
#define NCLS 20
#define WROW 32            // f64 weights per channel row, padded to 256 B

// ---- workspace layout (bytes) ----
#define OFF_W64   0          // double wpad[512*32] = 131072
#define OFF_B64   131072     // double b64[25]      = 200 (pad to 131328)
#define OFF_ORDER 131328     // int    order[64*1024]   = 262144
#define OFF_SBOX  393472     // float4 sbox[64*1024]    = 1048576
#define OFF_SCLS  1442048    // int    scls[64*1024]    = 262144
#define OFF_VALID 1704192    // u64    validW[64*16]    = 8192
#define OFF_MASK  1712384    // u64    masksT[64][16][1024] = 8388608
#define OFF_SUMM  10100992   // u32    summ32[64][16]   = 4096 -> end 10105088

// ---------------- kernel 0: weights -> f64 + zero validW/summ32 --------------
__global__ __launch_bounds__(256) void k_cvt(const float* __restrict__ w,
                                             const float* __restrict__ bias,
                                             double* __restrict__ wpad,
                                             double* __restrict__ b64,
                                             u64* __restrict__ validW,
                                             u32* __restrict__ summ32)
{
    int idx = blockIdx.x * 256 + threadIdx.x;
    if (idx < 512 * WROW) {
        int c = idx >> 5, o = idx & 31;
        wpad[idx] = (o < NOUT) ? (double)w[o * 512 + c] : 0.0;
    }
    if (idx < NOUT) b64[idx] = (double)bias[idx];
    if (idx < NB * 16) { validW[idx] = 0ull; summ32[idx] = 0u; }
}

// ---------------- f64 epilogue: sigmoid/softmax/argmax + box decode ----------
__device__ __forceinline__ void epilogue(const double* __restrict__ acc,
                                         const double* __restrict__ b64,
                                         int n, int gi,
                                         float* __restrict__ boxes_out,
                                         float* __restrict__ scores_out,
                                         float* __restrict__ cls_out)
{
    double p[NOUT];
#pragma unroll
    for (int o = 0; o < NOUT; ++o) p[o] = acc[o] + b64[o];

    double conf = 1.0 / (1.0 + exp(-p[0]));
    double m = p[1]; int ci = 0;
#pragma unroll
    for (int i = 2; i <= NCLS; ++i) {
        if (p[i] > m) { m = p[i]; ci = i - 1; }
    }
    double ssum = 0.0;
#pragma unroll
    for (int i = 0; i < NCLS; ++i) ssum += exp(p[1 + i] - m);
    double best = conf / ssum;

    int gx = n & 31, gy = n >> 5;
    double sx = 1.0 / (1.0 + exp(-p[21]));
    double sy = 1.0 / (1.0 + exp(-p[22]));
    double cx = (sx + (double)gx) * 32.0;
    double cy = (sy + (double)gy) * 32.0;
    double bw = exp(p[23]), bh = exp(p[24]);
    double x1 = (cx - bw * 0.5) * (1.0 / 1024.0);
    double y1 = (cy - bh * 0.5) * (1.0 / 1024.0);
    double x2 = (cx + bw * 0.5) * (1.0 / 1024.0);
    double y2 = (cy + bh * 0.5) * (1.0 / 1024.0);
    x1 = fmin(fmax(x1, 0.0), 1.0); y1 = fmin(fmax(y1, 0.0), 1.0);
    x2 = fmin(fmax(x2, 0.0), 1.0); y2 = fmin(fmax(y2, 0.0), 1.0);

    ((float4*)boxes_out)[gi] = make_float4((float)x1, (float)y1, (float)x2, (float)y2);
    scores_out[gi] = (float)best;
    cls_out[gi]    = (float)ci;
}

// ---------------- kernel 1: f64 MFMA GEMM, LDS-staged, pd unioned (R13) ------
__global__ __launch_bounds__(256, 4) void k_main(const float* __restrict__ feat,
                                                 const double* __restrict__ wpad_g,
                                                 const double* __restrict__ b64,
                                                 float* __restrict__ boxes_out,
                                                 float* __restrict__ scores_out,
                                                 float* __restrict__ cls_out)
{
    __shared__ __align__(16) char smem[32768];
    float*  AbF = (float*)smem;                    // [2][32*64] floats
    double* BbF = (double*)(smem + 16384);         // [2][32*32] doubles
    double (*pd)[33] = (double(*)[33])smem;        // [64][33], post-loop reuse

    const int b   = blockIdx.y;
    const int tid = threadIdx.x;
    const int l   = tid & 63;
    const int wv  = tid >> 6;
    const int pg  = wv >> 1;          // position half (32 pos)
    const int oh  = wv & 1;           // out half (16 outs)
    const int n0  = blockIdx.x * 64;

    // --- runtime D-row calibration: A[m][0]=m, B[0][n]=1 => D[m][n]=m -------
    double ca = ((l >> 4) == 0) ? (double)(l & 15) : 0.0;
    double cb = ((l >> 4) == 0) ? 1.0 : 0.0;
    f64x4 cd = {0.0, 0.0, 0.0, 0.0};
    cd = __builtin_amdgcn_mfma_f64_16x16x4f64(ca, cb, cd, 0, 0, 0);
    int rmap[4];
#pragma unroll
    for (int v = 0; v < 4; ++v) {
        int r = (int)(cd[v] + 0.5);
        rmap[v] = (r < 0) ? 0 : (r > 15 ? 15 : r);
    }

    const float* __restrict__ featb = feat + (size_t)b * 512 * NPOS + n0;

#define A_SRC(C0, IT) (((const float4*)(featb + (size_t)((C0) + wv*8 + (IT)*4 + (l>>4)) * NPOS)) + (l & 15))
#define B_SRC(C0, IT) (((const double2*)(wpad_g + (size_t)((C0) + wv*8 + (IT)*4 + (l>>4)) * WROW)) + (l & 15))
#define A_DST(BUF, IT) ((float4*)(AbF + (BUF)*2048 + (wv*8 + (IT)*4) * 64 + l*4))
#define B_DST(BUF, IT) ((double2*)(BbF + (BUF)*1024 + (wv*8 + (IT)*4) * 32 + l*2))

    f64x4 acc0 = {0.0, 0.0, 0.0, 0.0};   // pos frag 0 (pg*32+0..15) x out-half
    f64x4 acc1 = {0.0, 0.0, 0.0, 0.0};   // pos frag 1 (pg*32+16..31)

    // prologue: stage chunk 0
    float4  ra0 = *A_SRC(0, 0), ra1 = *A_SRC(0, 1);
    double2 rb0 = *B_SRC(0, 0), rb1 = *B_SRC(0, 1);
    *A_DST(0, 0) = ra0;  *A_DST(0, 1) = ra1;
    *B_DST(0, 0) = rb0;  *B_DST(0, 1) = rb1;
    __syncthreads();

#pragma unroll 1
    for (int t = 0; t < 16; ++t) {
        const int buf = t & 1;
        const bool more = (t + 1) < 16;
        const int c1 = (t + 1) * 32;
        if (more) {                       // issue next-chunk loads (hide under MFMA)
            ra0 = *A_SRC(c1, 0);  ra1 = *A_SRC(c1, 1);
            rb0 = *B_SRC(c1, 0);  rb1 = *B_SRC(c1, 1);
        }
#pragma unroll
        for (int s = 0; s < 8; ++s) {     // 8 k-steps x 4 ch
            const int rowA = buf*2048 + (4*s + (l >> 4)) * 64 + pg * 32 + (l & 15);
            const int rowB = buf*1024 + (4*s + (l >> 4)) * 32 + oh * 16 + (l & 15);
            double av0 = (double)AbF[rowA];
            double av1 = (double)AbF[rowA + 16];
            double bv  = BbF[rowB];
            acc0 = __builtin_amdgcn_mfma_f64_16x16x4f64(av0, bv, acc0, 0, 0, 0);
            acc1 = __builtin_amdgcn_mfma_f64_16x16x4f64(av1, bv, acc1, 0, 0, 0);
        }
        if (more) {                       // write next chunk into alt buffer
            *A_DST(buf ^ 1, 0) = ra0;  *A_DST(buf ^ 1, 1) = ra1;
            *B_DST(buf ^ 1, 0) = rb0;  *B_DST(buf ^ 1, 1) = rb1;
        }
        __syncthreads();
    }
#undef A_SRC
#undef B_SRC
#undef A_DST
#undef B_DST

    // dump D to LDS as [pos][out] with calibrated row map (smem reused)
#pragma unroll
    for (int v = 0; v < 4; ++v) {
        int r0 = pg * 32 + rmap[v];
        pd[r0][oh * 16 + (l & 15)]      = acc0[v];
        pd[r0 + 16][oh * 16 + (l & 15)] = acc1[v];
    }
    __syncthreads();

    if (tid < 64) {
        double acc[NOUT];
#pragma unroll
        for (int o = 0; o < NOUT; ++o) acc[o] = pd[tid][o];
        int n = n0 + tid;
        epilogue(acc, b64, n, b * NPOS + n, boxes_out, scores_out, cls_out);
    }
}

// ---------------- kernel 2: barrier-free rank sort ---------------------------
// Stable descending argsort via rank counting: rank_i = #{j : key_j > key_i
// or (key_j == key_i and j < i)}. Grid (4,64) = 256 blocks (1/CU); each
// thread owns one position; j-loop reads LDS keys as uint4 broadcasts (free).
// One barrier total (vs bitonic's 55). Scatters order/sbox/scls/validW.
__global__ __launch_bounds__(256) void k_rank(const float* __restrict__ scores,
                                              const float* __restrict__ boxes,
                                              const float* __restrict__ cls,
                                              int* __restrict__ order,
                                              float4* __restrict__ sbox,
                                              int* __restrict__ scls,
                                              u64* __restrict__ validW)
{
    __shared__ u32 keys[NPOS];
    const int b = blockIdx.y, tid = threadIdx.x;
    const int p = blockIdx.x * 256 + tid;

    for (int q = tid; q < NPOS; q += 256) {
        u32 bits = __float_as_uint(scores[b * NPOS + q]);
        keys[q] = ~(bits | 0x80000000u);   // descending-monotone (scores >= 0)
    }
    __syncthreads();

    const u32 ki = keys[p];
    int rank = 0;
    const uint4* k4 = (const uint4*)keys;
#pragma unroll 4
    for (int j4 = 0; j4 < NPOS / 4; ++j4) {
        uint4 kv = k4[j4];                 // same addr all lanes -> broadcast
        int j = j4 * 4;
        rank += (int)(kv.x > ki) + (int)((kv.x == ki) & (j + 0 < p));
        rank += (int)(kv.y > ki) + (int)((kv.y == ki) & (j + 1 < p));
        rank += (int)(kv.z > ki) + (int)((kv.z == ki) & (j + 2 < p));
        rank += (int)(kv.w > ki) + (int)((kv.w == ki) & (j + 3 < p));
    }

    order[b * NPOS + rank] = p;
    sbox [b * NPOS + rank] = ((const float4*)boxes)[b * NPOS + p];
    scls [b * NPOS + rank] = (int)cls[b * NPOS + p];
    float sc = __uint_as_float((~ki) & 0x7fffffffu);
    if (sc > 0.01f)
        atomicOr(&validW[b * 16 + (rank >> 6)], 1ull << (rank & 63));
}

// ---------------- kernel 3: suppression mask, ballot + sparse store ----------
__global__ __launch_bounds__(64) void k_mask(const float4* __restrict__ sbox,
                                             const int* __restrict__ scls,
                                             u64* __restrict__ masksT,
                                             u32* __restrict__ summ32)
{
    __shared__ float4 boxl[256];
    __shared__ float2 acl[256];
    const int wc  = blockIdx.x;
    const int w   = wc >> 2, chunk = wc & 3;
    const int b   = blockIdx.y;
    const int lane = threadIdx.x;
    const int i0   = chunk * 256;
    const int imax = (w + 1) * 64;            // rows that can suppress into word w
    u64* __restrict__ mcol = masksT + (((size_t)b * 16 + w) << 10);

    const int jg = w * 64 + lane;
    float4 bj = sbox[b * NPOS + jg];
    float  aj = (bj.z - bj.x) * (bj.w - bj.y);
    int    cj = scls[b * NPOS + jg];

    int iend = imax - i0;
    if (iend > 256) iend = 256;
    if (iend <= 0) return;                    // whole chunk above diagonal

    for (int i = lane; i < iend; i += 64) {
        float4 bb = sbox[b * NPOS + i0 + i];
        boxl[i] = bb;
        acl[i]  = make_float2((bb.z - bb.x) * (bb.w - bb.y),
                              __int_as_float(scls[b * NPOS + i0 + i]));
    }
    __syncthreads();

#pragma unroll 1
    for (int t = 0; t < 256; t += 64) {       // 64-row tiles (= summary granule)
        if (t >= iend) break;
        u64 myword = 0ull;
#pragma unroll 1
        for (int s = 0; s < 64; s += 8) {
            u64 bits[8];
#pragma unroll
            for (int u = 0; u < 8; ++u) {
                int i = t + s + u;
                float4 bi = boxl[i];          // wave-uniform broadcast
                float2 ac = acl[i];
                float xx1 = fmaxf(bi.x, bj.x), yy1 = fmaxf(bi.y, bj.y);
                float xx2 = fminf(bi.z, bj.z), yy2 = fminf(bi.w, bj.w);
                float ww = fmaxf(1e-28f, xx2 - xx1);
                float hh = fmaxf(1e-28f, yy2 - yy1);
                float inter = ww * hh;
                float uni = ac.x + aj - inter;
                bool sup = (__float_as_int(ac.y) == cj) && (uni > 0.0f) &&
                           (inter > 0.5f * uni) && (jg > i0 + i) && (i < iend);
                bits[u] = __ballot(sup);
            }
#pragma unroll
            for (int u = 0; u < 8; ++u)
                myword = (lane == s + u) ? bits[u] : myword;
        }
        bool nz = __any(myword != 0ull);
        if (nz) {
            mcol[i0 + t + lane] = myword;
            if (lane == 0)
                atomicOr(&summ32[b * 16 + ((i0 + t) >> 6)], 1u << w);
        }
    }
}

// ---------------- kernel 4: summary-driven suppression scan ------------------
__global__ __launch_bounds__(64) void k_scan(const u64* __restrict__ validW,
                                             const u64* __restrict__ masksT,
                                             const u32* __restrict__ summ32,
                                             const int* __restrict__ order,
                                             float* __restrict__ keep_out)
{
    int b = blockIdx.x, lane = threadIdx.x;
    u64 keep = (lane < 16) ? validW[b * 16 + lane] : 0ull;
    u32 sv   = (lane < 16) ? summ32[b * 16 + lane] : 0u;
    const u64* M = masksT + ((size_t)b << 14);    // [16 words][1024 rows]
    int myrow = lane >> 4;
    int myw   = lane & 15;

#pragma unroll 1
    for (int G = 0; G < 16; ++G) {                // 64-row groups
        u32 gm = (u32)__shfl((int)sv, G);         // word-flags for this group
        if (gm == 0u) continue;
#pragma unroll 1
        for (int g4 = 0; g4 < 16; ++g4) {         // 4-row subgroups
            u64 cur = 0ull;
            if ((gm >> myw) & 1u)
                cur = M[((size_t)myw << 10) + G * 64 + g4 * 4 + myrow];
            if (__any(cur != 0ull)) {
#pragma unroll
                for (int r = 0; r < 4; ++r) {
                    int i = G * 64 + g4 * 4 + r;
                    u64 kw = __shfl(keep, i >> 6);
                    if ((kw >> (i & 63)) & 1ull) {
                        u64 mm = __shfl(cur, r * 16 + myw);
                        if (lane < 16) keep &= ~mm;
                    }
                }
            }
        }
    }

#pragma unroll
    for (int t = 0; t < 16; ++t) {
        int ppos = t * 64 + lane;
        u64 kw = __shfl(keep, t);
        float v = ((kw >> lane) & 1ull) ? 1.0f : 0.0f;
        keep_out[b * NPOS + order[b * NPOS + ppos]] = v;
    }
}

// ------------------------------------------------------------------------------
extern "C" void kernel_launch(void* const* d_in, const int* in_sizes, int n_in,
                              void* d_out, int out_size, void* d_ws, size_t ws_size,
                              hipStream_t stream)
{
    const float* feat = (const float*)d_in[0];
    const float* w    = (const float*)d_in[1];
    const float* bias = (const float*)d_in[2];

    float* out = (float*)d_out;
    float* boxes_out  = out;
    float* scores_out = out + NB * NPOS * 4;
    float* cls_out    = out + NB * NPOS * 5;
    float* keep_out   = out + NB * NPOS * 6;

    char* ws = (char*)d_ws;
    double* wpad  = (double*)(ws + OFF_W64);
    double* b64   = (double*)(ws + OFF_B64);
    int*    order = (int*)   (ws + OFF_ORDER);
    float4* sbox  = (float4*)(ws + OFF_SBOX);
    int*    scls  = (int*)   (ws + OFF_SCLS);
    u64*    validW= (u64*)   (ws + OFF_VALID);
    u64*    masksT= (u64*)   (ws + OFF_MASK);
    u32*    summ32= (u32*)   (ws + OFF_SUMM);

    hipLaunchKernelGGL(k_cvt,  dim3(64),     dim3(256), 0, stream, w, bias, wpad,
                       b64, validW, summ32);
    hipLaunchKernelGGL(k_main, dim3(16, 64), dim3(256), 0, stream, feat, wpad, b64,
                       boxes_out, scores_out, cls_out);
    hipLaunchKernelGGL(k_rank, dim3(4, 64),  dim3(256), 0, stream, scores_out,
                       boxes_out, cls_out, order, sbox, scls, validW);
    hipLaunchKernelGGL(k_mask, dim3(64, 64), dim3(64),  0, stream, sbox, scls,
                       masksT, summ32);
    hipLaunchKernelGGL(k_scan, dim3(64),     dim3(64),  0, stream, validW, masksT,
                       summ32, order, keep_out);
}